// Round 8
// baseline (879.017 us; speedup 1.0000x reference)
//
#include <hip/hip_runtime.h>
#include <hip/hip_bf16.h>
#include <math.h>

#define BB 16
#define SS 2048
#define DD 512
#define NDOCS 200000
#define TOPK 5
#define EPSN 1e-12f
#define NEG_INF (-3.0e38f)

#define NB3 782                 // blocks: 782*256 = 200192 docs (tail clamped)

typedef short s16x8 __attribute__((ext_vector_type(8)));
typedef float f32x4 __attribute__((ext_vector_type(4)));

__device__ __forceinline__ short f2bf(float f) {
    __bf16 b = (__bf16)f;
    short s;
    __builtin_memcpy(&s, &b, 2);
    return s;
}

__device__ __forceinline__ void gload_lds16(const void* g, void* l) {
    __builtin_amdgcn_global_load_lds(
        (const __attribute__((address_space(1))) void*)g,
        (__attribute__((address_space(3))) void*)l, 16, 0, 0);
}

// ---------------- K1: partial mean pool: partial[32][16][512] ----------------
__global__ __launch_bounds__(128) void k1_mean_partial(
    const float* __restrict__ hs, float* __restrict__ partial) {
    int b = blockIdx.y, sc = blockIdx.x;
    int t = threadIdx.x;
    const float4* src = (const float4*)(hs + (size_t)(b * SS + sc * 64) * DD);
    float4 acc = {0.f, 0.f, 0.f, 0.f};
    for (int s = 0; s < 64; ++s) {
        float4 v = src[(size_t)s * 128 + t];
        acc.x += v.x; acc.y += v.y; acc.z += v.z; acc.w += v.w;
    }
    ((float4*)partial)[(size_t)(sc * BB + b) * 128 + t] = acc;
}

// ---------------- K1b: reduce partials -> mean[16][512] ----------------
__global__ __launch_bounds__(128) void k1b_mean_reduce(
    const float* __restrict__ partial, float* __restrict__ mean) {
    int b = blockIdx.y, jc = blockIdx.x;
    int j = jc * 128 + threadIdx.x;
    float s = 0.f;
    for (int c = 0; c < 32; ++c) s += partial[(size_t)(c * BB + b) * DD + j];
    mean[(size_t)b * DD + j] = s * (1.0f / 2048.0f);
}

// ---------------- K2a: qtmp[b][j] = mean[b] . Wq[j] + bq[j] ----------------
__global__ __launch_bounds__(256) void k2a_q_gemv(
    const float* __restrict__ mean, const float* __restrict__ Wq,
    const float* __restrict__ bq, float* __restrict__ qtmp) {
    int b = blockIdx.y, jc = blockIdx.x;
    int t = threadIdx.x;
    int r = t >> 4, c = t & 15;
    int row = jc * 16 + r;
    const float4* wr = (const float4*)(Wq + (size_t)row * DD);
    const float4* mv = (const float4*)(mean + (size_t)b * DD);
    float acc = 0.f;
#pragma unroll
    for (int it = 0; it < 8; ++it) {
        int k4 = c + it * 16;
        float4 w = wr[k4], m = mv[k4];
        acc = fmaf(w.x, m.x, acc); acc = fmaf(w.y, m.y, acc);
        acc = fmaf(w.z, m.z, acc); acc = fmaf(w.w, m.w, acc);
    }
#pragma unroll
    for (int m = 1; m < 16; m <<= 1) acc += __shfl_xor(acc, m);
    if (c == 0) qtmp[(size_t)b * DD + row] = acc + bq[row];
}

// ---------------- K2b: l2-normalize qtmp -> qv ----------------
__global__ __launch_bounds__(256) void k2b_q_norm(
    const float* __restrict__ qtmp, float* __restrict__ qv) {
    int b = blockIdx.x, t = threadIdx.x;
    __shared__ float red[4];
    float a0 = qtmp[(size_t)b * DD + t];
    float a1 = qtmp[(size_t)b * DD + t + 256];
    float ss = a0 * a0 + a1 * a1;
#pragma unroll
    for (int m = 1; m < 64; m <<= 1) ss += __shfl_xor(ss, m);
    if ((t & 63) == 0) red[t >> 6] = ss;
    __syncthreads();
    float inv = 1.0f / fmaxf(sqrtf(red[0] + red[1] + red[2] + red[3]), EPSN);
    qv[(size_t)b * DD + t] = a0 * inv;
    qv[(size_t)b * DD + t + 256] = a1 * inv;
}

// ---------------- K3: batch-split streaming scan ----------------
// 782 blocks x 256 thr (4 waves). Block covers 256 docs; wave w computes
// batches 4w..4w+3 for all 256 docs (R=4 docs/lane: row = bid*256 + r*64 + lane).
// Per 4-dim chunk: 4 broadcast ds_read_b128 + 80 FMA + 4 vmem -> VALU:LDS = 20:1.
// The 4 waves stream identical doc lines; L1/L2 absorb the redundancy.
__global__ __launch_bounds__(256, 1) void k3_scores(
    const float* __restrict__ docs, const float* __restrict__ qv,
    float* __restrict__ cand_s, int* __restrict__ cand_i) {
    __shared__ float qS[BB * DD];   // 32KB, [b][k] verbatim

    int t = threadIdx.x;
    int w = t >> 6, lane = t & 63;

    // stage q table once (2048 float4 units over 256 threads)
#pragma unroll
    for (int jj = 0; jj < 8; ++jj) {
        int u = ((w * 8 + jj) << 6) + lane;
        gload_lds16(qv + (size_t)u * 4, (void*)&qS[(w * 8 + jj) * 256]);
    }
    __syncthreads();

    long bid = blockIdx.x;
    long row0 = bid * 256 + lane;

    const float4* dp[4];
    bool valid[4];
#pragma unroll
    for (int r = 0; r < 4; ++r) {
        long row = row0 + r * 64;
        valid[r] = (row < NDOCS);
        if (row > NDOCS - 1) row = NDOCS - 1;
        dp[r] = (const float4*)(docs + row * DD);
    }
    const float4* qb = (const float4*)(qS + (size_t)(w * 4) * DD);  // qb[b*128 + c]

    float acc[4][4];   // [r][b]
    float nrm[4];
#pragma unroll
    for (int r = 0; r < 4; ++r) {
        nrm[r] = 0.f;
#pragma unroll
        for (int b = 0; b < 4; ++b) acc[r][b] = 0.f;
    }

    float4 cur[4], nxt[4];
#pragma unroll
    for (int r = 0; r < 4; ++r) cur[r] = dp[r][0];

#pragma unroll 4
    for (int c = 0; c < 128; ++c) {
        int cn = (c < 127) ? c + 1 : 127;
#pragma unroll
        for (int r = 0; r < 4; ++r) nxt[r] = dp[r][cn];
        float4 q0 = qb[0 * 128 + c];
        float4 q1 = qb[1 * 128 + c];
        float4 q2 = qb[2 * 128 + c];
        float4 q3 = qb[3 * 128 + c];
#pragma unroll
        for (int r = 0; r < 4; ++r) {
            float4 e = cur[r];
            nrm[r]    = fmaf(e.x, e.x, fmaf(e.y, e.y, fmaf(e.z, e.z, fmaf(e.w, e.w, nrm[r]))));
            acc[r][0] = fmaf(e.x, q0.x, fmaf(e.y, q0.y, fmaf(e.z, q0.z, fmaf(e.w, q0.w, acc[r][0]))));
            acc[r][1] = fmaf(e.x, q1.x, fmaf(e.y, q1.y, fmaf(e.z, q1.z, fmaf(e.w, q1.w, acc[r][1]))));
            acc[r][2] = fmaf(e.x, q2.x, fmaf(e.y, q2.y, fmaf(e.z, q2.z, fmaf(e.w, q2.w, acc[r][2]))));
            acc[r][3] = fmaf(e.x, q3.x, fmaf(e.y, q3.y, fmaf(e.z, q3.z, fmaf(e.w, q3.w, acc[r][3]))));
        }
#pragma unroll
        for (int r = 0; r < 4; ++r) cur[r] = nxt[r];
    }

    float invn[4];
#pragma unroll
    for (int r = 0; r < 4; ++r)
        invn[r] = 1.0f / fmaxf(sqrtf(nrm[r]), EPSN);

    // per-wave top-5 over the block's 256 docs for its 4 batches
#pragma unroll 1
    for (int bi = 0; bi < 4; ++bi) {
        int b = w * 4 + bi;
        float v[4]; int nn[4];
#pragma unroll
        for (int r = 0; r < 4; ++r) {
            nn[r] = (int)(row0 + r * 64);
            v[r] = valid[r] ? acc[r][bi] * invn[r] : NEG_INF;
        }
        float lvv[TOPK]; int lii[TOPK];
#pragma unroll
        for (int rd = 0; rd < TOPK; ++rd) {
            float bv = v[0]; int bx = nn[0];
#pragma unroll
            for (int r = 1; r < 4; ++r)
                if (v[r] > bv || (v[r] == bv && nn[r] < bx)) { bv = v[r]; bx = nn[r]; }
#pragma unroll
            for (int mm = 1; mm < 64; mm <<= 1) {
                float ov = __shfl_xor(bv, mm);
                int   oi = __shfl_xor(bx, mm);
                if (ov > bv || (ov == bv && oi < bx)) { bv = ov; bx = oi; }
            }
            lvv[rd] = bv; lii[rd] = bx;
#pragma unroll
            for (int r = 0; r < 4; ++r)
                if (nn[r] == bx) v[r] = NEG_INF;
        }
        if (lane == 0) {
#pragma unroll
            for (int rd = 0; rd < TOPK; ++rd) {
                cand_s[(bid * BB + b) * TOPK + rd] = lvv[rd];
                cand_i[(bid * BB + b) * TOPK + rd] = lii[rd];
            }
        }
    }
}

// ---------------- K4a: merge top-5, softmax, context, outputs ----------------
__global__ __launch_bounds__(256) void k4a_topk_ctx(
    const float* __restrict__ docs, const float* __restrict__ cand_s,
    const int* __restrict__ cand_i, float* __restrict__ ctx,
    float* __restrict__ outp) {
    int b = blockIdx.x, t = threadIdx.x;
    __shared__ float sv[256];
    __shared__ int   si[256];
    __shared__ float topv[TOPK];
    __shared__ int   topi[TOPK];
    __shared__ float red[4];
    __shared__ float nrm5[TOPK];
    __shared__ float wts[TOPK];

    float lv[TOPK]; int li[TOPK];
#pragma unroll
    for (int r = 0; r < TOPK; ++r) { lv[r] = NEG_INF; li[r] = 0x7fffffff; }

    for (int j = t; j < NB3 * TOPK; j += 256) {
        int blk = j / TOPK, r = j - blk * TOPK;
        float s = cand_s[(long)blk * (BB * TOPK) + b * TOPK + r];
        int  di = cand_i[(long)blk * (BB * TOPK) + b * TOPK + r];
        if (s > lv[TOPK - 1] || (s == lv[TOPK - 1] && di < li[TOPK - 1])) {
            lv[TOPK - 1] = s; li[TOPK - 1] = di;
#pragma unroll
            for (int k = TOPK - 1; k > 0; --k) {
                if (lv[k] > lv[k - 1] || (lv[k] == lv[k - 1] && li[k] < li[k - 1])) {
                    float tv = lv[k]; lv[k] = lv[k - 1]; lv[k - 1] = tv;
                    int   ti = li[k]; li[k] = li[k - 1]; li[k - 1] = ti;
                }
            }
        }
    }

    int p = 0;
    for (int r = 0; r < TOPK; ++r) {
        float hv = (p < TOPK) ? lv[p] : NEG_INF;
        int   hi = (p < TOPK) ? li[p] : 0x7fffffff;
        sv[t] = hv; si[t] = hi;
        __syncthreads();
        for (int off = 128; off > 0; off >>= 1) {
            if (t < off) {
                float ov = sv[t + off]; int oi = si[t + off];
                if (ov > sv[t] || (ov == sv[t] && oi < si[t])) { sv[t] = ov; si[t] = oi; }
            }
            __syncthreads();
        }
        if (t == 0) { topv[r] = sv[0]; topi[r] = si[0]; }
        __syncthreads();
        if (hv == topv[r] && hi == topi[r]) ++p;
        __syncthreads();
    }

    for (int r = 0; r < TOPK; ++r) {
        const float* dr = docs + (size_t)topi[r] * DD;
        float s2 = dr[t] * dr[t] + dr[t + 256] * dr[t + 256];
#pragma unroll
        for (int m = 1; m < 64; m <<= 1) s2 += __shfl_xor(s2, m);
        if ((t & 63) == 0) red[t >> 6] = s2;
        __syncthreads();
        if (t == 0) nrm5[r] = sqrtf(red[0] + red[1] + red[2] + red[3]);
        __syncthreads();
    }

    if (t == 0) {
        float m = topv[0];
        float e[TOPK], s = 0.f;
#pragma unroll
        for (int r = 0; r < TOPK; ++r) { e[r] = expf(topv[r] - m); s += e[r]; }
#pragma unroll
        for (int r = 0; r < TOPK; ++r) wts[r] = e[r] / s;
    }
    __syncthreads();

    for (int j = t; j < DD; j += 256) {
        float c = 0.f;
#pragma unroll
        for (int r = 0; r < TOPK; ++r)
            c += wts[r] * docs[(size_t)topi[r] * DD + j] / fmaxf(nrm5[r], EPSN);
        ctx[(size_t)b * DD + j] = c;
    }

    if (t < TOPK) {
        outp[b * TOPK + t] = topv[t];
        outp[BB * TOPK + b * TOPK + t] = (float)topi[t];
    }
}

// ---------------- K4b: ctxb[b][j] = ctx[b] . Wg[j, 512:1024] + bg[j] --------
__global__ __launch_bounds__(256) void k4b_ctxb_gemv(
    const float* __restrict__ ctx, const float* __restrict__ Wg,
    const float* __restrict__ bgt, float* __restrict__ ctxb) {
    int b = blockIdx.y, jc = blockIdx.x;
    int t = threadIdx.x;
    int r = t >> 4, c = t & 15;
    int row = jc * 16 + r;
    const float4* wr = (const float4*)(Wg + (size_t)row * (2 * DD) + DD);
    const float4* mv = (const float4*)(ctx + (size_t)b * DD);
    float acc = 0.f;
#pragma unroll
    for (int it = 0; it < 8; ++it) {
        int k4 = c + it * 16;
        float4 w = wr[k4], m = mv[k4];
        acc = fmaf(w.x, m.x, acc); acc = fmaf(w.y, m.y, acc);
        acc = fmaf(w.z, m.z, acc); acc = fmaf(w.w, m.w, acc);
    }
#pragma unroll
    for (int m = 1; m < 16; m <<= 1) acc += __shfl_xor(acc, m);
    if (c == 0) ctxb[(size_t)b * DD + row] = acc + bgt[row];
}

// ---------------- K5: bf16 MFMA gate GEMM + fused epilogue ----------------
#define BK 32
__global__ __launch_bounds__(512, 2) void k5_gemm_fused(
    const float* __restrict__ hs, const float* __restrict__ Wg,
    const float* __restrict__ ctx, const float* __restrict__ ctxb,
    float* __restrict__ outF) {
    __shared__ short At[128][BK];
    __shared__ short Bt[512][BK];
    __shared__ float ctxLds[DD];
    __shared__ float ctxbLds[DD];

    int bm = blockIdx.x;
    int t = threadIdx.x;
    int wv = t >> 6, lane = t & 63, ln = lane & 15, kg = lane >> 4;
    int wm = (wv >> 2) * 64, wn = (wv & 3) * 128;
    int bbatch = bm >> 4;

    ctxLds[t]  = ctx[(size_t)bbatch * DD + t];
    ctxbLds[t] = ctxb[(size_t)bbatch * DD + t];

    float4 pf[5][2];
    auto gload = [&](int kt) {
        {
            const float* src = hs + (size_t)(bm * 128 + (t >> 2)) * DD + kt * BK + (t & 3) * 8;
            pf[0][0] = ((const float4*)src)[0];
            pf[0][1] = ((const float4*)src)[1];
        }
#pragma unroll
        for (int i = 0; i < 4; ++i) {
            int u = t + i * 512;
            const float* src = Wg + (size_t)(u >> 2) * (2 * DD) + kt * BK + (u & 3) * 8;
            pf[1 + i][0] = ((const float4*)src)[0];
            pf[1 + i][1] = ((const float4*)src)[1];
        }
    };
    auto cvt1 = [&](float4 lo, float4 hi) {
        s16x8 cv;
        cv[0] = f2bf(lo.x); cv[1] = f2bf(lo.y); cv[2] = f2bf(lo.z); cv[3] = f2bf(lo.w);
        cv[4] = f2bf(hi.x); cv[5] = f2bf(hi.y); cv[6] = f2bf(hi.z); cv[7] = f2bf(hi.w);
        return cv;
    };
    auto cvtwrite = [&]() {
        {
            int row = t >> 2, slot = t & 3;
            int sl = slot ^ ((row >> 1) & 3);
            *(s16x8*)(&At[row][sl * 8]) = cvt1(pf[0][0], pf[0][1]);
        }
#pragma unroll
        for (int i = 0; i < 4; ++i) {
            int u = t + i * 512;
            int row = u >> 2, slot = u & 3;
            int sl = slot ^ ((row >> 1) & 3);
            *(s16x8*)(&Bt[row][sl * 8]) = cvt1(pf[1 + i][0], pf[1 + i][1]);
        }
    };

    f32x4 accv[4][8];
#pragma unroll
    for (int i = 0; i < 4; ++i)
#pragma unroll
        for (int j = 0; j < 8; ++j) accv[i][j] = (f32x4){0.f, 0.f, 0.f, 0.f};

    gload(0);
    for (int kt = 0; kt < DD / BK; ++kt) {
        __syncthreads();
        cvtwrite();
        if (kt + 1 < DD / BK) gload(kt + 1);
        __syncthreads();
        s16x8 af[4], bfr[8];
#pragma unroll
        for (int mi = 0; mi < 4; ++mi) {
            int row = wm + mi * 16 + ln;
            int sl = kg ^ ((row >> 1) & 3);
            af[mi] = *(const s16x8*)&At[row][sl * 8];
        }
#pragma unroll
        for (int nj = 0; nj < 8; ++nj) {
            int row = wn + nj * 16 + ln;
            int sl = kg ^ ((row >> 1) & 3);
            bfr[nj] = *(const s16x8*)&Bt[row][sl * 8];
        }
#pragma unroll
        for (int mi = 0; mi < 4; ++mi)
#pragma unroll
            for (int nj = 0; nj < 8; ++nj)
                accv[mi][nj] = __builtin_amdgcn_mfma_f32_16x16x32_bf16(
                    af[mi], bfr[nj], accv[mi][nj], 0, 0, 0);
    }

#pragma unroll
    for (int mi = 0; mi < 4; ++mi)
#pragma unroll
        for (int nj = 0; nj < 8; ++nj)
#pragma unroll
            for (int r = 0; r < 4; ++r) {
                int ri = wm + mi * 16 + kg * 4 + r;
                int ci = wn + nj * 16 + ln;
                size_t grow = (size_t)bm * 128 + ri;
                float logit = accv[mi][nj][r] + ctxbLds[ci];
                float g = __builtin_amdgcn_rcpf(1.0f + __expf(-logit));
                float h = hs[grow * DD + ci];
                float cx = ctxLds[ci];
                outF[grow * DD + ci] = g * h + (1.0f - g) * cx;
            }
}

// ---------------- launch ----------------
extern "C" void kernel_launch(void* const* d_in, const int* in_sizes, int n_in,
                              void* d_out, int out_size, void* d_ws, size_t ws_size,
                              hipStream_t stream) {
    const float* hs   = (const float*)d_in[0];
    const float* docs = (const float*)d_in[1];
    const float* Wq   = (const float*)d_in[2];
    const float* bq   = (const float*)d_in[3];
    const float* Wg   = (const float*)d_in[4];
    const float* bgt  = (const float*)d_in[5];
    float* outp = (float*)d_out;
    float* ws = (float*)d_ws;

    float* partial = ws;                               // 32*16*512
    float* mean    = partial + 32 * BB * DD;
    float* qtmp    = mean + BB * DD;
    float* qv      = qtmp + BB * DD;
    float* ctx     = qv + BB * DD;
    float* ctxb    = ctx + BB * DD;
    float* cand_s  = ctxb + BB * DD;                   // NB3*16*5 = 62560
    int*   cand_i  = (int*)(cand_s + (size_t)NB3 * BB * TOPK);

    k1_mean_partial<<<dim3(32, BB), 128, 0, stream>>>(hs, partial);
    k1b_mean_reduce<<<dim3(4, BB), 128, 0, stream>>>(partial, mean);
    k2a_q_gemv<<<dim3(32, BB), 256, 0, stream>>>(mean, Wq, bq, qtmp);
    k2b_q_norm<<<BB, 256, 0, stream>>>(qtmp, qv);
    k3_scores<<<NB3, 256, 0, stream>>>(docs, qv, cand_s, cand_i);
    k4a_topk_ctx<<<BB, 256, 0, stream>>>(docs, cand_s, cand_i, ctx, outp);
    k4b_ctxb_gemv<<<dim3(32, BB), 256, 0, stream>>>(ctx, Wg, bgt, ctxb);
    k5_gemm_fused<<<256, 512, 0, stream>>>(hs, Wg, ctx, ctxb,
                                           outp + 2 * BB * TOPK);
}

// Round 9
// 257.252 us; speedup vs baseline: 3.4169x; 3.4169x over previous
//
#include <hip/hip_runtime.h>
#include <hip/hip_bf16.h>
#include <math.h>

#define BB 16
#define SS 2048
#define DD 512
#define NDOCS 200000
#define TOPK 5
#define EPSN 1e-12f
#define NEG_INF (-3.0e38f)

#define NB3 782                 // blocks for K3
#define NW3 (NB3 * 4)           // 3128 scanning waves
#define NT3 (NDOCS / 16)        // 12500 16-doc tiles (exact)
#define QSTR 520                // padded q row stride (shorts): bank-conflict-free

typedef short s16x8 __attribute__((ext_vector_type(8)));
typedef float f32x4 __attribute__((ext_vector_type(4)));

__device__ __forceinline__ short f2bf(float f) {
    __bf16 b = (__bf16)f;
    short s;
    __builtin_memcpy(&s, &b, 2);
    return s;
}

__device__ __forceinline__ void gload_lds16(const void* g, void* l) {
    __builtin_amdgcn_global_load_lds(
        (const __attribute__((address_space(1))) void*)g,
        (__attribute__((address_space(3))) void*)l, 16, 0, 0);
}

// ---------------- K1: partial mean pool: partial[32][16][512] ----------------
__global__ __launch_bounds__(128) void k1_mean_partial(
    const float* __restrict__ hs, float* __restrict__ partial) {
    int b = blockIdx.y, sc = blockIdx.x;
    int t = threadIdx.x;
    const float4* src = (const float4*)(hs + (size_t)(b * SS + sc * 64) * DD);
    float4 acc = {0.f, 0.f, 0.f, 0.f};
    for (int s = 0; s < 64; ++s) {
        float4 v = src[(size_t)s * 128 + t];
        acc.x += v.x; acc.y += v.y; acc.z += v.z; acc.w += v.w;
    }
    ((float4*)partial)[(size_t)(sc * BB + b) * 128 + t] = acc;
}

// ---------------- K1b: reduce partials -> mean[16][512] ----------------
__global__ __launch_bounds__(128) void k1b_mean_reduce(
    const float* __restrict__ partial, float* __restrict__ mean) {
    int b = blockIdx.y, jc = blockIdx.x;
    int j = jc * 128 + threadIdx.x;
    float s = 0.f;
    for (int c = 0; c < 32; ++c) s += partial[(size_t)(c * BB + b) * DD + j];
    mean[(size_t)b * DD + j] = s * (1.0f / 2048.0f);
}

// ---------------- K2a: qtmp[b][j] = mean[b] . Wq[j] + bq[j] ----------------
__global__ __launch_bounds__(256) void k2a_q_gemv(
    const float* __restrict__ mean, const float* __restrict__ Wq,
    const float* __restrict__ bq, float* __restrict__ qtmp) {
    int b = blockIdx.y, jc = blockIdx.x;
    int t = threadIdx.x;
    int r = t >> 4, c = t & 15;
    int row = jc * 16 + r;
    const float4* wr = (const float4*)(Wq + (size_t)row * DD);
    const float4* mv = (const float4*)(mean + (size_t)b * DD);
    float acc = 0.f;
#pragma unroll
    for (int it = 0; it < 8; ++it) {
        int k4 = c + it * 16;
        float4 w = wr[k4], m = mv[k4];
        acc = fmaf(w.x, m.x, acc); acc = fmaf(w.y, m.y, acc);
        acc = fmaf(w.z, m.z, acc); acc = fmaf(w.w, m.w, acc);
    }
#pragma unroll
    for (int m = 1; m < 16; m <<= 1) acc += __shfl_xor(acc, m);
    if (c == 0) qtmp[(size_t)b * DD + row] = acc + bq[row];
}

// ---------------- K2b: l2-normalize qtmp -> qv ----------------
__global__ __launch_bounds__(256) void k2b_q_norm(
    const float* __restrict__ qtmp, float* __restrict__ qv) {
    int b = blockIdx.x, t = threadIdx.x;
    __shared__ float red[4];
    float a0 = qtmp[(size_t)b * DD + t];
    float a1 = qtmp[(size_t)b * DD + t + 256];
    float ss = a0 * a0 + a1 * a1;
#pragma unroll
    for (int m = 1; m < 64; m <<= 1) ss += __shfl_xor(ss, m);
    if ((t & 63) == 0) red[t >> 6] = ss;
    __syncthreads();
    float inv = 1.0f / fmaxf(sqrtf(red[0] + red[1] + red[2] + red[3]), EPSN);
    qv[(size_t)b * DD + t] = a0 * inv;
    qv[(size_t)b * DD + t + 256] = a1 * inv;
}

// ---------------- K3: barrier-free streaming MFMA scan ----------------
// 782 blocks x 256 thr (4 waves). Wave owns 16-doc tiles (grid-stride).
// Lane: bq=lane&15 -> doc row in tile (A) / batch col (B); kg=lane>>4 -> k-slice.
// Per 32-dim chunk: 2 global dwordx4 + 2 ds_read_b128 + 3 MFMA + ~40 VALU.
// q in LDS as bf16 hi/lo planes, row stride 520 shorts (bank-free, 2-way).
// Numerics identical to R3's verified hi/lo 3-MFMA split; norms exact fp32.
__global__ __launch_bounds__(256) void k3_scores(
    const float* __restrict__ docs, const float* __restrict__ qv,
    float* __restrict__ cand_s, int* __restrict__ cand_i) {
    __shared__ short qS[2][BB * QSTR];   // hi plane, lo plane: 2 x 16.25KB

    int t = threadIdx.x;
    int w = t >> 6, lane = t & 63;
    int bq = lane & 15, kg = lane >> 4;

    // build q hi/lo tables (8192 floats over 256 threads)
    for (int u = t; u < BB * DD; u += 256) {
        int b = u >> 9, k = u & 511;
        float f = qv[u];
        unsigned uu = __float_as_uint(f);
        qS[0][b * QSTR + k] = (short)(uu >> 16);
        qS[1][b * QSTR + k] = f2bf(f - __uint_as_float(uu & 0xFFFF0000u));
    }
    __syncthreads();

    int gw = blockIdx.x * 4 + w;

    float lv[TOPK]; int li[TOPK];
#pragma unroll
    for (int r = 0; r < TOPK; ++r) { lv[r] = NEG_INF; li[r] = 0x7fffffff; }

    auto ins = [&](float s, int di) {
        if (s > lv[4] || (s == lv[4] && di < li[4])) {
            lv[4] = s; li[4] = di;
#pragma unroll
            for (int k = 4; k > 0; --k) {
                if (lv[k] > lv[k - 1] || (lv[k] == lv[k - 1] && li[k] < li[k - 1])) {
                    float tv = lv[k]; lv[k] = lv[k - 1]; lv[k - 1] = tv;
                    int   ti = li[k]; li[k] = li[k - 1]; li[k - 1] = ti;
                }
            }
        }
    };

    const short* qh_base = &qS[0][bq * QSTR + kg * 8];
    const short* ql_base = &qS[1][bq * QSTR + kg * 8];

    long tt = gw;
    const float* dpt = docs + ((long)tt * 16 + bq) * DD + kg * 8;
    // depth-2 flat prefetch: A = chunk c, B = chunk c+1
    f32x4 A0 = *(const f32x4*)(dpt);
    f32x4 A1 = *(const f32x4*)(dpt + 4);
    f32x4 B0 = *(const f32x4*)(dpt + 32);
    f32x4 B1 = *(const f32x4*)(dpt + 36);

    while (tt < NT3) {
        long tt2 = (tt + NW3 < NT3) ? tt + NW3 : tt;
        const float* dpn = docs + (tt2 * 16 + bq) * DD + kg * 8;

        f32x4 acc1 = {0.f, 0.f, 0.f, 0.f};
        f32x4 acc2 = {0.f, 0.f, 0.f, 0.f};
        float nrm = 0.f;

#pragma unroll
        for (int c = 0; c < 16; ++c) {
            f32x4 C0, C1;
            if (c + 2 < 16) {
                C0 = *(const f32x4*)(dpt + (c + 2) * 32);
                C1 = *(const f32x4*)(dpt + (c + 2) * 32 + 4);
            } else {
                C0 = *(const f32x4*)(dpn + (c - 14) * 32);
                C1 = *(const f32x4*)(dpn + (c - 14) * 32 + 4);
            }
            float ef[8] = {A0[0], A0[1], A0[2], A0[3], A1[0], A1[1], A1[2], A1[3]};
            s16x8 ah, al;
#pragma unroll
            for (int i = 0; i < 8; ++i) {
                unsigned u = __float_as_uint(ef[i]);
                ah[i] = (short)(u >> 16);
                al[i] = f2bf(ef[i] - __uint_as_float(u & 0xFFFF0000u));
                nrm = fmaf(ef[i], ef[i], nrm);
            }
            s16x8 qh = *(const s16x8*)(qh_base + c * 32);
            s16x8 ql = *(const s16x8*)(ql_base + c * 32);
            acc1 = __builtin_amdgcn_mfma_f32_16x16x32_bf16(ah, qh, acc1, 0, 0, 0);
            acc2 = __builtin_amdgcn_mfma_f32_16x16x32_bf16(ah, ql, acc2, 0, 0, 0);
            acc2 = __builtin_amdgcn_mfma_f32_16x16x32_bf16(al, qh, acc2, 0, 0, 0);
            A0 = B0; A1 = B1; B0 = C0; B1 = C1;
        }

        // tile epilogue: exact norms via 2 shfl; C layout col=bq, row=kg*4+r
        float nn = nrm + __shfl_xor(nrm, 16);
        nn += __shfl_xor(nn, 32);
        float invn = 1.0f / fmaxf(sqrtf(nn), EPSN);
        f32x4 acct = acc1 + acc2;
#pragma unroll
        for (int r = 0; r < 4; ++r) {
            float iv = __shfl(invn, kg * 4 + r);     // lane kg*4+r holds that doc's norm
            ins(acct[r] * iv, (int)(tt * 16 + kg * 4 + r));
        }

        tt += NW3;
        dpt = dpn;
    }

    // merge top-5 across the 4 kg groups (xor 16, 32 preserve batch = lane&15)
#pragma unroll
    for (int step = 16; step <= 32; step <<= 1) {
        float ov[TOPK]; int oi[TOPK];
#pragma unroll
        for (int r = 0; r < TOPK; ++r) {
            ov[r] = __shfl_xor(lv[r], step);
            oi[r] = __shfl_xor(li[r], step);
        }
#pragma unroll
        for (int r = 0; r < TOPK; ++r) ins(ov[r], oi[r]);
    }

    if (kg == 0) {
#pragma unroll
        for (int r = 0; r < TOPK; ++r) {
            cand_s[((long)gw * BB + bq) * TOPK + r] = lv[r];
            cand_i[((long)gw * BB + bq) * TOPK + r] = li[r];
        }
    }
}

// ---------------- K4a: merge top-5, softmax, context, outputs ----------------
__global__ __launch_bounds__(256) void k4a_topk_ctx(
    const float* __restrict__ docs, const float* __restrict__ cand_s,
    const int* __restrict__ cand_i, float* __restrict__ ctx,
    float* __restrict__ outp) {
    int b = blockIdx.x, t = threadIdx.x;
    __shared__ float sv[256];
    __shared__ int   si[256];
    __shared__ float topv[TOPK];
    __shared__ int   topi[TOPK];
    __shared__ float red[4];
    __shared__ float nrm5[TOPK];
    __shared__ float wts[TOPK];

    float lv[TOPK]; int li[TOPK];
#pragma unroll
    for (int r = 0; r < TOPK; ++r) { lv[r] = NEG_INF; li[r] = 0x7fffffff; }

    for (int j = t; j < NW3 * TOPK; j += 256) {
        int blk = j / TOPK, r = j - blk * TOPK;
        float s = cand_s[(long)blk * (BB * TOPK) + b * TOPK + r];
        int  di = cand_i[(long)blk * (BB * TOPK) + b * TOPK + r];
        if (s > lv[TOPK - 1] || (s == lv[TOPK - 1] && di < li[TOPK - 1])) {
            lv[TOPK - 1] = s; li[TOPK - 1] = di;
#pragma unroll
            for (int k = TOPK - 1; k > 0; --k) {
                if (lv[k] > lv[k - 1] || (lv[k] == lv[k - 1] && li[k] < li[k - 1])) {
                    float tv = lv[k]; lv[k] = lv[k - 1]; lv[k - 1] = tv;
                    int   ti = li[k]; li[k] = li[k - 1]; li[k - 1] = ti;
                }
            }
        }
    }

    int p = 0;
    for (int r = 0; r < TOPK; ++r) {
        float hv = (p < TOPK) ? lv[p] : NEG_INF;
        int   hi = (p < TOPK) ? li[p] : 0x7fffffff;
        sv[t] = hv; si[t] = hi;
        __syncthreads();
        for (int off = 128; off > 0; off >>= 1) {
            if (t < off) {
                float ov = sv[t + off]; int oi = si[t + off];
                if (ov > sv[t] || (ov == sv[t] && oi < si[t])) { sv[t] = ov; si[t] = oi; }
            }
            __syncthreads();
        }
        if (t == 0) { topv[r] = sv[0]; topi[r] = si[0]; }
        __syncthreads();
        if (hv == topv[r] && hi == topi[r]) ++p;
        __syncthreads();
    }

    for (int r = 0; r < TOPK; ++r) {
        const float* dr = docs + (size_t)topi[r] * DD;
        float s2 = dr[t] * dr[t] + dr[t + 256] * dr[t + 256];
#pragma unroll
        for (int m = 1; m < 64; m <<= 1) s2 += __shfl_xor(s2, m);
        if ((t & 63) == 0) red[t >> 6] = s2;
        __syncthreads();
        if (t == 0) nrm5[r] = sqrtf(red[0] + red[1] + red[2] + red[3]);
        __syncthreads();
    }

    if (t == 0) {
        float m = topv[0];
        float e[TOPK], s = 0.f;
#pragma unroll
        for (int r = 0; r < TOPK; ++r) { e[r] = expf(topv[r] - m); s += e[r]; }
#pragma unroll
        for (int r = 0; r < TOPK; ++r) wts[r] = e[r] / s;
    }
    __syncthreads();

    for (int j = t; j < DD; j += 256) {
        float c = 0.f;
#pragma unroll
        for (int r = 0; r < TOPK; ++r)
            c += wts[r] * docs[(size_t)topi[r] * DD + j] / fmaxf(nrm5[r], EPSN);
        ctx[(size_t)b * DD + j] = c;
    }

    if (t < TOPK) {
        outp[b * TOPK + t] = topv[t];
        outp[BB * TOPK + b * TOPK + t] = (float)topi[t];
    }
}

// ---------------- K4b: ctxb[b][j] = ctx[b] . Wg[j, 512:1024] + bg[j] --------
__global__ __launch_bounds__(256) void k4b_ctxb_gemv(
    const float* __restrict__ ctx, const float* __restrict__ Wg,
    const float* __restrict__ bgt, float* __restrict__ ctxb) {
    int b = blockIdx.y, jc = blockIdx.x;
    int t = threadIdx.x;
    int r = t >> 4, c = t & 15;
    int row = jc * 16 + r;
    const float4* wr = (const float4*)(Wg + (size_t)row * (2 * DD) + DD);
    const float4* mv = (const float4*)(ctx + (size_t)b * DD);
    float acc = 0.f;
#pragma unroll
    for (int it = 0; it < 8; ++it) {
        int k4 = c + it * 16;
        float4 w = wr[k4], m = mv[k4];
        acc = fmaf(w.x, m.x, acc); acc = fmaf(w.y, m.y, acc);
        acc = fmaf(w.z, m.z, acc); acc = fmaf(w.w, m.w, acc);
    }
#pragma unroll
    for (int m = 1; m < 16; m <<= 1) acc += __shfl_xor(acc, m);
    if (c == 0) ctxb[(size_t)b * DD + row] = acc + bgt[row];
}

// ---------------- K5: bf16 MFMA gate GEMM + fused epilogue ----------------
#define BK 32
__global__ __launch_bounds__(512, 2) void k5_gemm_fused(
    const float* __restrict__ hs, const float* __restrict__ Wg,
    const float* __restrict__ ctx, const float* __restrict__ ctxb,
    float* __restrict__ outF) {
    __shared__ short At[128][BK];
    __shared__ short Bt[512][BK];
    __shared__ float ctxLds[DD];
    __shared__ float ctxbLds[DD];

    int bm = blockIdx.x;
    int t = threadIdx.x;
    int wv = t >> 6, lane = t & 63, ln = lane & 15, kg = lane >> 4;
    int wm = (wv >> 2) * 64, wn = (wv & 3) * 128;
    int bbatch = bm >> 4;

    ctxLds[t]  = ctx[(size_t)bbatch * DD + t];
    ctxbLds[t] = ctxb[(size_t)bbatch * DD + t];

    float4 pf[5][2];
    auto gload = [&](int kt) {
        {
            const float* src = hs + (size_t)(bm * 128 + (t >> 2)) * DD + kt * BK + (t & 3) * 8;
            pf[0][0] = ((const float4*)src)[0];
            pf[0][1] = ((const float4*)src)[1];
        }
#pragma unroll
        for (int i = 0; i < 4; ++i) {
            int u = t + i * 512;
            const float* src = Wg + (size_t)(u >> 2) * (2 * DD) + kt * BK + (u & 3) * 8;
            pf[1 + i][0] = ((const float4*)src)[0];
            pf[1 + i][1] = ((const float4*)src)[1];
        }
    };
    auto cvt1 = [&](float4 lo, float4 hi) {
        s16x8 cv;
        cv[0] = f2bf(lo.x); cv[1] = f2bf(lo.y); cv[2] = f2bf(lo.z); cv[3] = f2bf(lo.w);
        cv[4] = f2bf(hi.x); cv[5] = f2bf(hi.y); cv[6] = f2bf(hi.z); cv[7] = f2bf(hi.w);
        return cv;
    };
    auto cvtwrite = [&]() {
        {
            int row = t >> 2, slot = t & 3;
            int sl = slot ^ ((row >> 1) & 3);
            *(s16x8*)(&At[row][sl * 8]) = cvt1(pf[0][0], pf[0][1]);
        }
#pragma unroll
        for (int i = 0; i < 4; ++i) {
            int u = t + i * 512;
            int row = u >> 2, slot = u & 3;
            int sl = slot ^ ((row >> 1) & 3);
            *(s16x8*)(&Bt[row][sl * 8]) = cvt1(pf[1 + i][0], pf[1 + i][1]);
        }
    };

    f32x4 accv[4][8];
#pragma unroll
    for (int i = 0; i < 4; ++i)
#pragma unroll
        for (int j = 0; j < 8; ++j) accv[i][j] = (f32x4){0.f, 0.f, 0.f, 0.f};

    gload(0);
    for (int kt = 0; kt < DD / BK; ++kt) {
        __syncthreads();
        cvtwrite();
        if (kt + 1 < DD / BK) gload(kt + 1);
        __syncthreads();
        s16x8 af[4], bfr[8];
#pragma unroll
        for (int mi = 0; mi < 4; ++mi) {
            int row = wm + mi * 16 + ln;
            int sl = kg ^ ((row >> 1) & 3);
            af[mi] = *(const s16x8*)&At[row][sl * 8];
        }
#pragma unroll
        for (int nj = 0; nj < 8; ++nj) {
            int row = wn + nj * 16 + ln;
            int sl = kg ^ ((row >> 1) & 3);
            bfr[nj] = *(const s16x8*)&Bt[row][sl * 8];
        }
#pragma unroll
        for (int mi = 0; mi < 4; ++mi)
#pragma unroll
            for (int nj = 0; nj < 8; ++nj)
                accv[mi][nj] = __builtin_amdgcn_mfma_f32_16x16x32_bf16(
                    af[mi], bfr[nj], accv[mi][nj], 0, 0, 0);
    }

#pragma unroll
    for (int mi = 0; mi < 4; ++mi)
#pragma unroll
        for (int nj = 0; nj < 8; ++nj)
#pragma unroll
            for (int r = 0; r < 4; ++r) {
                int ri = wm + mi * 16 + kg * 4 + r;
                int ci = wn + nj * 16 + ln;
                size_t grow = (size_t)bm * 128 + ri;
                float logit = accv[mi][nj][r] + ctxbLds[ci];
                float g = __builtin_amdgcn_rcpf(1.0f + __expf(-logit));
                float h = hs[grow * DD + ci];
                float cx = ctxLds[ci];
                outF[grow * DD + ci] = g * h + (1.0f - g) * cx;
            }
}

// ---------------- launch ----------------
extern "C" void kernel_launch(void* const* d_in, const int* in_sizes, int n_in,
                              void* d_out, int out_size, void* d_ws, size_t ws_size,
                              hipStream_t stream) {
    const float* hs   = (const float*)d_in[0];
    const float* docs = (const float*)d_in[1];
    const float* Wq   = (const float*)d_in[2];
    const float* bq   = (const float*)d_in[3];
    const float* Wg   = (const float*)d_in[4];
    const float* bgt  = (const float*)d_in[5];
    float* outp = (float*)d_out;
    float* ws = (float*)d_ws;

    float* partial = ws;                               // 32*16*512
    float* mean    = partial + 32 * BB * DD;
    float* qtmp    = mean + BB * DD;
    float* qv      = qtmp + BB * DD;
    float* ctx     = qv + BB * DD;
    float* ctxb    = ctx + BB * DD;
    float* cand_s  = ctxb + BB * DD;                   // NW3*16*5 = 250240
    int*   cand_i  = (int*)(cand_s + (size_t)NW3 * BB * TOPK);

    k1_mean_partial<<<dim3(32, BB), 128, 0, stream>>>(hs, partial);
    k1b_mean_reduce<<<dim3(4, BB), 128, 0, stream>>>(partial, mean);
    k2a_q_gemv<<<dim3(32, BB), 256, 0, stream>>>(mean, Wq, bq, qtmp);
    k2b_q_norm<<<BB, 256, 0, stream>>>(qtmp, qv);
    k3_scores<<<NB3, 256, 0, stream>>>(docs, qv, cand_s, cand_i);
    k4a_topk_ctx<<<BB, 256, 0, stream>>>(docs, cand_s, cand_i, ctx, outp);
    k4b_ctxb_gemv<<<dim3(32, BB), 256, 0, stream>>>(ctx, Wg, bgt, ctxb);
    k5_gemm_fused<<<256, 512, 0, stream>>>(hs, Wg, ctx, ctxb,
                                           outp + 2 * BB * TOPK);
}